// Round 8
// baseline (66.564 us; speedup 1.0000x reference)
//
#include <hip/hip_runtime.h>

#define N_TOK 8192
#define D_DIM 1024
#define E_NUM 8
#define D4 (D_DIM / 4)
#define SCAN_BLOCKS 32              // N_TOK / 256
#define PAD_BLOCKS_PER_E 1024       // covers worst case 8192 pad rows, 8/block
#define PAD_ROWS 8

typedef unsigned long long u64;
typedef float f32x4 __attribute__((ext_vector_type(4)));

// Workspace:
//   dest[N][E]  int : global rank of token n in expert e, or -1 (256 KB)
//   counts_i[E] int
// Packing: lo = experts 0..3, hi = experts 4..7, 16-bit fields (counts <= 8192).

__device__ __forceinline__ u64 pack4(const int4 a) {
    return (u64)a.x | ((u64)a.y << 16) | ((u64)a.z << 32) | ((u64)a.w << 48);
}

// K1: single-kernel scan — VERBATIM Round-6 version (LDS ping-pong).
// 32 blocks x 256 threads, 1 token/thread; each block redundantly reads the
// whole mask (8 MB aggregate, L2-served) so there is no dependency kernel.
__global__ __launch_bounds__(256) void scan_all_kernel(
    const int4* __restrict__ mask4,       // hot_mask as [N][2] int4
    int* __restrict__ dest,               // [N, E] (ws)
    int* __restrict__ counts_i,           // [E]    (ws)
    float* __restrict__ out_tags,         // [E, N]
    float* __restrict__ out_counts)       // [E]
{
    const int bid = blockIdx.x;
    const int t   = threadIdx.x;
    const int n   = bid * 256 + t;

    u64 pre_lo = 0, pre_hi = 0, all_lo = 0, all_hi = 0, my_lo = 0, my_hi = 0;
    for (int k = 0; k < SCAN_BLOCKS; ++k) {
        const int tok = k * 256 + t;
        const u64 lo = pack4(mask4[(size_t)tok * 2]);
        const u64 hi = pack4(mask4[(size_t)tok * 2 + 1]);
        all_lo += lo; all_hi += hi;
        if (k < bid)  { pre_lo += lo; pre_hi += hi; }
        if (k == bid) { my_lo  = lo; my_hi  = hi; }
    }

    __shared__ u64 s1[256], s2[256];

    // Reduce all -> grand totals.
    s1[t] = all_lo; s2[t] = all_hi; __syncthreads();
    for (int off = 128; off > 0; off >>= 1) {
        if (t < off) { s1[t] += s1[t + off]; s2[t] += s2[t + off]; }
        __syncthreads();
    }
    const u64 tot_lo = s1[0], tot_hi = s2[0];
    __syncthreads();

    // Reduce pre -> offset of this block.
    s1[t] = pre_lo; s2[t] = pre_hi; __syncthreads();
    for (int off = 128; off > 0; off >>= 1) {
        if (t < off) { s1[t] += s1[t + off]; s2[t] += s2[t + off]; }
        __syncthreads();
    }
    const u64 base_lo = s1[0], base_hi = s2[0];
    __syncthreads();

    // Inclusive scan of my -> within-block prefix.
    s1[t] = my_lo; s2[t] = my_hi; __syncthreads();
    for (int off = 1; off < 256; off <<= 1) {
        u64 p1 = 0, p2 = 0;
        if (t >= off) { p1 = s1[t - off]; p2 = s2[t - off]; }
        __syncthreads();
        if (t >= off) { s1[t] += p1; s2[t] += p2; }
        __syncthreads();
    }
    const u64 plo = (s1[t] - my_lo) + base_lo;   // global exclusive, packed
    const u64 phi = (s2[t] - my_hi) + base_hi;

    int d[8];
    #pragma unroll
    for (int e = 0; e < E_NUM; ++e) {
        const int sh = 16 * (e & 3);
        const int m  = (int)(((e < 4 ? my_lo : my_hi) >> sh) & 0xFFFF);
        const int r  = (int)(((e < 4 ? plo   : phi  ) >> sh) & 0xFFFF);
        d[e] = m ? r : -1;
        if (m) out_tags[(size_t)e * N_TOK + r] = (float)n;
    }

    int4* dest4 = (int4*)dest;
    int4 d0; d0.x = d[0]; d0.y = d[1]; d0.z = d[2]; d0.w = d[3];
    int4 d1; d1.x = d[4]; d1.y = d[5]; d1.z = d[6]; d1.w = d[7];
    dest4[(size_t)n * 2]     = d0;
    dest4[(size_t)n * 2 + 1] = d1;

    // Counts + tag pad fill.
    int cnt[8];
    #pragma unroll
    for (int e = 0; e < E_NUM; ++e) {
        cnt[e] = (int)(((e < 4 ? tot_lo : tot_hi) >> (16 * (e & 3))) & 0xFFFF);
    }
    if (bid == 0 && t < E_NUM) {
        counts_i[t]   = cnt[t];
        out_counts[t] = (float)cnt[t];
    }
    #pragma unroll
    for (int e = 0; e < E_NUM; ++e) {
        const int idx = cnt[e] + n;          // thread n covers pad slot cnt+n
        if (idx < N_TOK) out_tags[(size_t)e * N_TOK + idx] = 0.0f;
    }
}

// K2: fused scatter + consolidated pad-fill.
//   Token branch: VERBATIM Round-6 (scalar per-e dest/score loads, NT stores).
//   Pad branch:   consolidated — expert e = p>>10, 8 rows from cnt_e + (p&1023)*8.
__global__ __launch_bounds__(256) void dispatch_scatter_kernel(
    const f32x4* __restrict__ x,        // [N, D/4]
    const float* __restrict__ score,    // [N, E]
    const int* __restrict__ dest,       // [N, E]
    const int* __restrict__ counts_i,   // [E]
    f32x4* __restrict__ out)            // [E*N, D/4]
{
    const int b = blockIdx.x;
    const int c = threadIdx.x;

    if (b < N_TOK) {
        const int n = b;
        const f32x4 xv = x[(size_t)n * D4 + c];
        #pragma unroll
        for (int e = 0; e < E_NUM; ++e) {
            const int r = dest[(size_t)n * E_NUM + e];   // uniform per block
            if (r >= 0) {
                const float s = score[(size_t)n * E_NUM + e];
                const f32x4 v = xv * s;
                __builtin_nontemporal_store(
                    v, &out[((size_t)e * N_TOK + r) * D4 + c]);
            }
        }
    } else {
        const int p  = b - N_TOK;               // 0 .. 8*1024-1
        const int e  = p >> 10;
        const int k  = p & (PAD_BLOCKS_PER_E - 1);
        const int r0 = counts_i[e] + k * PAD_ROWS;
        if (r0 >= N_TOK) return;
        const f32x4 z = (f32x4)0.0f;
        #pragma unroll
        for (int i = 0; i < PAD_ROWS; ++i) {
            const int r = r0 + i;
            if (r < N_TOK) {
                __builtin_nontemporal_store(
                    z, &out[((size_t)e * N_TOK + r) * D4 + c]);
            }
        }
    }
}

extern "C" void kernel_launch(void* const* d_in, const int* in_sizes, int n_in,
                              void* d_out, int out_size, void* d_ws, size_t ws_size,
                              hipStream_t stream) {
    const float* x        = (const float*)d_in[0];
    const int*   hot_mask = (const int*)d_in[1];
    const float* score    = (const float*)d_in[2];

    float* out        = (float*)d_out;
    float* out_data   = out;                                  // [E, N, D]
    float* out_tags   = out + (size_t)E_NUM * N_TOK * D_DIM;  // [E, N]
    float* out_counts = out_tags + (size_t)E_NUM * N_TOK;     // [E]

    int* dest     = (int*)d_ws;                               // [N, E]
    int* counts_i = dest + (size_t)N_TOK * E_NUM;             // [E]

    scan_all_kernel<<<SCAN_BLOCKS, 256, 0, stream>>>(
        (const int4*)hot_mask, dest, counts_i, out_tags, out_counts);

    dispatch_scatter_kernel<<<N_TOK + E_NUM * PAD_BLOCKS_PER_E, 256, 0, stream>>>(
        (const f32x4*)x, score, dest, counts_i, (f32x4*)out_data);
}

// Round 9
// 59.297 us; speedup vs baseline: 1.1226x; 1.1226x over previous
//
#include <hip/hip_runtime.h>

#define N_TOK 8192
#define D_DIM 1024
#define E_NUM 8
#define D4 (D_DIM / 4)
#define SCAN_BLOCKS 32              // N_TOK / 256

typedef unsigned long long u64;
typedef float f32x4 __attribute__((ext_vector_type(4)));

// Workspace:
//   dest[N][E]  int : global rank of token n in expert e, or -1 (256 KB)
//   counts_i[E] int
// Packing: lo = experts 0..3, hi = experts 4..7, 16-bit fields (counts <= 8192).

__device__ __forceinline__ u64 pack4(const int4 a) {
    return (u64)a.x | ((u64)a.y << 16) | ((u64)a.z << 32) | ((u64)a.w << 48);
}

// K1: single-kernel scan, wave-shuffle edition (Round-7 K1 verbatim).
// 32 blocks x 256 threads; each block redundantly reads the whole mask
// (8 MB aggregate, L2-served) -> no dependency kernel. One __syncthreads.
__global__ __launch_bounds__(256) void scan_all_kernel(
    const int4* __restrict__ mask4,       // hot_mask as [N][2] int4
    int* __restrict__ dest,               // [N, E] (ws)
    int* __restrict__ counts_i,           // [E]    (ws)
    float* __restrict__ out_tags,         // [E, N]
    float* __restrict__ out_counts)       // [E]
{
    const int bid  = blockIdx.x;
    const int t    = threadIdx.x;
    const int lane = t & 63;
    const int wave = t >> 6;              // 0..3
    const int n    = bid * 256 + t;

    u64 pre_lo = 0, pre_hi = 0, all_lo = 0, all_hi = 0, my_lo = 0, my_hi = 0;
    for (int k = 0; k < SCAN_BLOCKS; ++k) {
        const int tok = k * 256 + t;
        const u64 lo = pack4(mask4[(size_t)tok * 2]);
        const u64 hi = pack4(mask4[(size_t)tok * 2 + 1]);
        all_lo += lo; all_hi += hi;
        if (k < bid)  { pre_lo += lo; pre_hi += hi; }
        if (k == bid) { my_lo  = lo; my_hi  = hi; }
    }

    // Wave-level inclusive scan of my.
    u64 sc_lo = my_lo, sc_hi = my_hi;
    #pragma unroll
    for (int off = 1; off < 64; off <<= 1) {
        const u64 a = __shfl_up(sc_lo, off, 64);
        const u64 b = __shfl_up(sc_hi, off, 64);
        if (lane >= off) { sc_lo += a; sc_hi += b; }
    }
    const u64 wsum_lo = __shfl(sc_lo, 63, 64);   // wave total of my
    const u64 wsum_hi = __shfl(sc_hi, 63, 64);

    // Butterfly sums of all and pre (every lane ends with the wave sum).
    u64 asum_lo = all_lo, asum_hi = all_hi, psum_lo = pre_lo, psum_hi = pre_hi;
    #pragma unroll
    for (int off = 1; off < 64; off <<= 1) {
        asum_lo += __shfl_xor(asum_lo, off, 64);
        asum_hi += __shfl_xor(asum_hi, off, 64);
        psum_lo += __shfl_xor(psum_lo, off, 64);
        psum_hi += __shfl_xor(psum_hi, off, 64);
    }

    __shared__ u64 lds[4][6];
    if (lane == 0) {
        lds[wave][0] = wsum_lo; lds[wave][1] = wsum_hi;
        lds[wave][2] = asum_lo; lds[wave][3] = asum_hi;
        lds[wave][4] = psum_lo; lds[wave][5] = psum_hi;
    }
    __syncthreads();

    u64 tot_lo = 0, tot_hi = 0, base_lo = 0, base_hi = 0, woff_lo = 0, woff_hi = 0;
    #pragma unroll
    for (int w = 0; w < 4; ++w) {
        tot_lo  += lds[w][2]; tot_hi  += lds[w][3];
        base_lo += lds[w][4]; base_hi += lds[w][5];
        if (w < wave) { woff_lo += lds[w][0]; woff_hi += lds[w][1]; }
    }

    // Global exclusive packed prefix for this token.
    const u64 plo = (sc_lo - my_lo) + woff_lo + base_lo;
    const u64 phi = (sc_hi - my_hi) + woff_hi + base_hi;

    int d[8];
    #pragma unroll
    for (int e = 0; e < E_NUM; ++e) {
        const int sh = 16 * (e & 3);
        const int m  = (int)(((e < 4 ? my_lo : my_hi) >> sh) & 0xFFFF);
        const int r  = (int)(((e < 4 ? plo   : phi  ) >> sh) & 0xFFFF);
        d[e] = m ? r : -1;
        if (m) out_tags[(size_t)e * N_TOK + r] = (float)n;
    }

    int4* dest4 = (int4*)dest;
    int4 d0; d0.x = d[0]; d0.y = d[1]; d0.z = d[2]; d0.w = d[3];
    int4 d1; d1.x = d[4]; d1.y = d[5]; d1.z = d[6]; d1.w = d[7];
    dest4[(size_t)n * 2]     = d0;
    dest4[(size_t)n * 2 + 1] = d1;

    int cnt[8];
    #pragma unroll
    for (int e = 0; e < E_NUM; ++e) {
        cnt[e] = (int)(((e < 4 ? tot_lo : tot_hi) >> (16 * (e & 3))) & 0xFFFF);
    }
    if (bid == 0 && t < E_NUM) {
        counts_i[t]   = cnt[t];
        out_counts[t] = (float)cnt[t];
    }
    // Tag pad fill: thread n covers slot cnt_e + n (covers all of [cnt, N)).
    #pragma unroll
    for (int e = 0; e < E_NUM; ++e) {
        const int idx = cnt[e] + n;
        if (idx < N_TOK) out_tags[(size_t)e * N_TOK + idx] = 0.0f;
    }
}

// K2: fused scatter + pad-fill.
//   Token branch: vectorized int4/float4 dest/score loads (Round-7 style).
//   Pad branch:   Round-6 verbatim — ONE row per block (empirically fastest).
__global__ __launch_bounds__(256) void dispatch_scatter_kernel(
    const f32x4* __restrict__ x,        // [N, D/4]
    const float* __restrict__ score,    // [N, E]
    const int* __restrict__ dest,       // [N, E]
    const int* __restrict__ counts_i,   // [E]
    f32x4* __restrict__ out)            // [E*N, D/4]
{
    const int b = blockIdx.x;
    const int c = threadIdx.x;

    if (b < N_TOK) {
        const int n = b;
        const f32x4 xv = x[(size_t)n * D4 + c];
        const int4 da = ((const int4*)dest)[(size_t)n * 2];
        const int4 db = ((const int4*)dest)[(size_t)n * 2 + 1];
        const float4 sa = ((const float4*)score)[(size_t)n * 2];
        const float4 sb = ((const float4*)score)[(size_t)n * 2 + 1];
        const int   de[8] = { da.x, da.y, da.z, da.w, db.x, db.y, db.z, db.w };
        const float se[8] = { sa.x, sa.y, sa.z, sa.w, sb.x, sb.y, sb.z, sb.w };

        #pragma unroll
        for (int e = 0; e < E_NUM; ++e) {
            const int r = de[e];
            if (r >= 0) {
                const f32x4 v = xv * se[e];
                __builtin_nontemporal_store(
                    v, &out[((size_t)e * N_TOK + r) * D4 + c]);
            }
        }
    } else {
        const int row = b - N_TOK;          // e*N + r
        const int e   = row >> 13;
        const int r   = row & (N_TOK - 1);
        if (r >= counts_i[e]) {
            const f32x4 z = (f32x4)0.0f;
            __builtin_nontemporal_store(z, &out[(size_t)row * D4 + c]);
        }
    }
}

extern "C" void kernel_launch(void* const* d_in, const int* in_sizes, int n_in,
                              void* d_out, int out_size, void* d_ws, size_t ws_size,
                              hipStream_t stream) {
    const float* x        = (const float*)d_in[0];
    const int*   hot_mask = (const int*)d_in[1];
    const float* score    = (const float*)d_in[2];

    float* out        = (float*)d_out;
    float* out_data   = out;                                  // [E, N, D]
    float* out_tags   = out + (size_t)E_NUM * N_TOK * D_DIM;  // [E, N]
    float* out_counts = out_tags + (size_t)E_NUM * N_TOK;     // [E]

    int* dest     = (int*)d_ws;                               // [N, E]
    int* counts_i = dest + (size_t)N_TOK * E_NUM;             // [E]

    scan_all_kernel<<<SCAN_BLOCKS, 256, 0, stream>>>(
        (const int4*)hot_mask, dest, counts_i, out_tags, out_counts);

    dispatch_scatter_kernel<<<N_TOK + E_NUM * N_TOK, 256, 0, stream>>>(
        (const f32x4*)x, score, dest, counts_i, (f32x4*)out_data);
}